// Round 2
// baseline (295.221 us; speedup 1.0000x reference)
//
#include <hip/hip_runtime.h>

#define NT 64
#define B_ 32
#define C_ 32
#define H_ 160
#define W_ 160
#define TH 20
#define TW 20
#define NPIX (TH*TW)     // 400
#define NRED (B_*NPIX)   // 12800
#define EPS 1e-5f

#define HP 40            // hlds channel stride (bf16): pixel step = 20 dwords -> clean 8-phase b128
#define WSL 33           // (fallback kernel only) wlds per-tap slab stride in co rows
#define WPACK_PER_TILE (9*2*64*8)   // 9216 bf16 per tile

typedef __bf16 bf16x8 __attribute__((ext_vector_type(8)));
typedef float  f32x4  __attribute__((ext_vector_type(4)));

// ============ Kernel A: per-(b,c)-plane coalesced stats + weight pre-pack ==
// Blocks [0, 1024): stats for plane (b,c). Blocks [1024, 1088): pack tile
// tl's weights into per-lane B-fragment order [tap][half][lane][8] bf16, so
// the fused kernel can load W-fragments straight from global (L2-hot) and
// needs no weight LDS at all.
__global__ __launch_bounds__(320) void statsA_kernel(const float* __restrict__ x,
                                                     float* __restrict__ ppS,
                                                     float* __restrict__ ppS2,
                                                     const float* __restrict__ conv_w,
                                                     __bf16* __restrict__ wpack) {
    int blk = blockIdx.x;          // b*32 + c
    if (blk >= B_*C_) {
        int tl = blk - B_*C_;
        const float* wsrc = conv_w + (long)tl * (C_*C_*9);
        __bf16* wdst = wpack + (long)tl * WPACK_PER_TILE;
        for (int f = threadIdx.x; f < WPACK_PER_TILE; f += 320) {
            int t    = f >> 10;          // tap 0..8
            int r    = f & 1023;
            int h    = r >> 9;           // co half 0..1
            int r2   = r & 511;
            int lane = r2 >> 3;          // 0..63
            int k    = r2 & 7;
            int mm   = lane & 15;
            int jg   = lane >> 4;
            int co   = h*16 + mm;
            int cin  = jg*8 + k;
            wdst[f] = (__bf16)wsrc[(co*C_ + cin)*9 + t];
        }
        return;
    }
    int b = blk >> 5;
    int c = blk & 31;
    const float* plane = x + ((long)(b*C_ + c)) * H_ * W_;

    int tid   = threadIdx.x;
    int col4  = tid % 40;          // f4 column (0..39), constant per thread
    int rbase = tid / 40;          // 0..7

    __shared__ float sh [8 * 321];
    __shared__ float sh2[8 * 321];

    #pragma unroll
    for (int tr = 0; tr < 8; ++tr) {
        float s = 0.f, s2 = 0.f;
        #pragma unroll
        for (int k = 0; k < 3; ++k) {
            int r20 = rbase + 8*k;
            if (r20 < 20) {
                int row = tr*20 + r20;
                float4 v = *(const float4*)(plane + row*W_ + col4*4);
                s  += v.x + v.y + v.z + v.w;
                s2 += v.x*v.x + v.y*v.y + v.z*v.z + v.w*v.w;
            }
        }
        sh [tr*321 + tid] = s;
        sh2[tr*321 + tid] = s2;
    }
    __syncthreads();

    if (tid < 64) {
        int tr = tid >> 3, tc = tid & 7;
        float ps = 0.f, ps2 = 0.f;
        #pragma unroll
        for (int rb = 0; rb < 8; ++rb)
            #pragma unroll
            for (int c5 = 0; c5 < 5; ++c5) {
                int t = tr*321 + rb*40 + tc*5 + c5;
                ps += sh[t]; ps2 += sh2[t];
            }
        int tl = tr*8 + tc;
        atomicAdd(&ppS [tl*C_ + c], ps);
        atomicAdd(&ppS2[tl*C_ + c], ps2);
    }
}

// ============ Kernel B (packed path): norm+relu + 9-tap MFMA conv + residual
// v3: no weight LDS -- W-fragments stream from pre-packed global (L2-hot).
// LDS = hlds only (38,976 B) -> 4 blocks/CU; launch_bounds(512,8) pins
// VGPR<=64 so occupancy is LDS-limited at 4 blocks (32 waves/CU).
__global__ __launch_bounds__(512, 8) void fused_packed(
        const float* __restrict__ x,
        const float* __restrict__ gamma,
        const float* __restrict__ beta,
        const float* __restrict__ conv_b,
        const float* __restrict__ ppS,
        const float* __restrict__ ppS2,
        const __bf16* __restrict__ wpack,
        float* __restrict__ out) {
    int blk = blockIdx.x;
    int tl = blk >> 5;
    int b  = blk & 31;
    int ti = (tl >> 3) * TH;
    int tj = (tl & 7)  * TW;
    int tid = threadIdx.x;

    // LDS: hlds [484 pix][40 ch] bf16 (zero halo ring) + BN coeffs
    __shared__ __align__(16) unsigned char smem[38976];
    __bf16* hlds   = (__bf16*)smem;
    float*  scale  = (float*)(smem + 38720);
    float*  shiftv = (float*)(smem + 38848);

    // ---- phase 0: zero halo ring + finalize BN coeffs ----
    if (tid < 420) {                       // 84 halo pixels x 5 uint4 (80 B each)
        int hp = tid / 5, q = tid - hp*5;
        int P;
        if      (hp < 22) P = hp;                    // row 0
        else if (hp < 44) P = 462 + (hp - 22);       // row 21
        else if (hp < 64) P = (hp - 43) * 22;        // col 0, rows 1..20
        else              P = (hp - 63) * 22 + 21;   // col 21, rows 1..20
        ((uint4*)smem)[P*5 + q] = uint4{0,0,0,0};
    }
    if (tid < C_) {
        int c = tid;
        float s   = ppS [tl*C_ + c];
        float s2  = ppS2[tl*C_ + c];
        float m   = s / (float)NRED;
        float var = s2 / (float)NRED - m*m;
        float rs  = rsqrtf(var + EPS);
        float g   = gamma[tl*C_ + c];
        scale[c]  = g * rs;
        shiftv[c] = beta[tl*C_ + c] - m * rs * g;
    }
    __syncthreads();

    // ---- phase 1: normalize+relu, 1 pixel x 8 channels per item, b128 write
    for (int idx = tid; idx < 4*NPIX; idx += 512) {   // 1600 items
        int cg = idx / NPIX;            // channel group 0..3
        int p  = idx - cg*NPIX;         // pixel 0..399 (lane-consecutive)
        int y  = p / 20;
        int xx = p - y*20;
        int c0 = cg*8;
        const float* ps = x + (((long)(b*C_ + c0)*H_ + ti + y)*W_ + tj + xx);
        float v[8];
        #pragma unroll
        for (int k = 0; k < 8; ++k) v[k] = ps[k * (H_*W_)];
        bf16x8 h;
        #pragma unroll
        for (int k = 0; k < 8; ++k)
            h[k] = (__bf16)fmaxf(v[k]*scale[c0+k] + shiftv[c0+k], 0.f);
        *(bf16x8*)&hlds[((y+1)*22 + xx + 1)*HP + c0] = h;
    }
    __syncthreads();

    // ---- phase 2: tap-outer GEMM; W from packed global, A from hlds ----
    int lane = tid & 63;
    int wv   = tid >> 6;            // wave 0..7
    int mm   = lane & 15;
    int jg   = lane >> 4;           // 0..3
    int j0   = jg * 8;
    float b0 = conv_b[tl*C_ + mm];
    float b1 = conv_b[tl*C_ + 16 + mm];
    const __bf16* wp = wpack + (long)tl * WPACK_PER_TILE + lane*8;

    auto store_chunk = [&](int chunk, f32x4 a0, f32x4 a1) {
        // D layout: col = lane&15 (co), row = jg*4 + r (pixel) -> 4 consecutive
        // pixels; runs of 4 never cross the 20-wide tile row.
        int pb = chunk*16 + jg*4;
        int py = pb / 20;
        int px = pb - py*20;
        long o0 = ((long)(b*C_ + mm)*H_ + ti + py)*W_ + tj + px;
        long o1 = o0 + (long)16*H_*W_;
        float4 x0 = *(const float4*)&x[o0];     // residual: L2-hot (read in phase 1)
        float4 x1 = *(const float4*)&x[o1];
        float4 r0 = make_float4(a0[0]+x0.x, a0[1]+x0.y, a0[2]+x0.z, a0[3]+x0.w);
        float4 r1 = make_float4(a1[0]+x1.x, a1[1]+x1.y, a1[2]+x1.z, a1[3]+x1.w);
        *(float4*)&out[o0] = r0;
        *(float4*)&out[o1] = r1;
    };

    // 3 chunks per wave (chunk = wv + 8*i); wave 0 takes chunk 24 afterwards
    const __bf16* ab[3];
    #pragma unroll
    for (int i = 0; i < 3; ++i) {
        int p  = (wv + 8*i)*16 + mm;
        int py = p / 20;
        int px = p - py*20;
        ab[i] = &hlds[(py*22 + px)*HP + j0];
    }
    f32x4 acc[3][2];
    #pragma unroll
    for (int i = 0; i < 3; ++i) {
        acc[i][0] = f32x4{b0,b0,b0,b0};
        acc[i][1] = f32x4{b1,b1,b1,b1};
    }
    #pragma unroll
    for (int tap = 0; tap < 9; ++tap) {
        const int ky = tap/3, kx = tap - (tap/3)*3;
        bf16x8 w0 = *(const bf16x8*)(wp + tap*1024);
        bf16x8 w1 = *(const bf16x8*)(wp + tap*1024 + 512);
        #pragma unroll
        for (int i = 0; i < 3; ++i) {
            bf16x8 af = *(const bf16x8*)(ab[i] + (ky*22 + kx)*HP);
            acc[i][0] = __builtin_amdgcn_mfma_f32_16x16x32_bf16(af, w0, acc[i][0], 0, 0, 0);
            acc[i][1] = __builtin_amdgcn_mfma_f32_16x16x32_bf16(af, w1, acc[i][1], 0, 0, 0);
        }
    }
    #pragma unroll
    for (int i = 0; i < 3; ++i) store_chunk(wv + 8*i, acc[i][0], acc[i][1]);

    if (wv == 0) {   // wave-uniform branch: the 25th chunk
        int p  = 24*16 + mm;
        int py = p / 20;
        int px = p - py*20;
        const __bf16* a3 = &hlds[(py*22 + px)*HP + j0];
        f32x4 c0v = f32x4{b0,b0,b0,b0};
        f32x4 c1v = f32x4{b1,b1,b1,b1};
        #pragma unroll
        for (int tap = 0; tap < 9; ++tap) {
            const int ky = tap/3, kx = tap - (tap/3)*3;
            bf16x8 w0 = *(const bf16x8*)(wp + tap*1024);
            bf16x8 w1 = *(const bf16x8*)(wp + tap*1024 + 512);
            bf16x8 af = *(const bf16x8*)(a3 + (ky*22 + kx)*HP);
            c0v = __builtin_amdgcn_mfma_f32_16x16x32_bf16(af, w0, c0v, 0, 0, 0);
            c1v = __builtin_amdgcn_mfma_f32_16x16x32_bf16(af, w1, c1v, 0, 0, 0);
        }
        store_chunk(24, c0v, c1v);
    }
}

// ============ Kernel B (fallback, ws too small): v2 kernel verbatim ========
__global__ __launch_bounds__(512, 4) void fused_lds(
        const float* __restrict__ x,
        const float* __restrict__ gamma,
        const float* __restrict__ beta,
        const float* __restrict__ conv_w,
        const float* __restrict__ conv_b,
        const float* __restrict__ ppS,
        const float* __restrict__ ppS2,
        float* __restrict__ out) {
    int blk = blockIdx.x;
    int tl = blk >> 5;
    int b  = blk & 31;
    int ti = (tl >> 3) * TH;
    int tj = (tl & 7)  * TW;
    int tid = threadIdx.x;

    __shared__ __align__(16) unsigned char smem[62656];
    __bf16* hlds   = (__bf16*)smem;
    __bf16* wlds   = (__bf16*)(smem + 38720);
    float*  scale  = (float*)(smem + 62400);
    float*  shiftv = (float*)(smem + 62528);

    if (tid < 420) {
        int hp = tid / 5, q = tid - hp*5;
        int P;
        if      (hp < 22) P = hp;
        else if (hp < 44) P = 462 + (hp - 22);
        else if (hp < 64) P = (hp - 43) * 22;
        else              P = (hp - 63) * 22 + 21;
        ((uint4*)smem)[P*5 + q] = uint4{0,0,0,0};
    }
    if (tid < C_) {
        int c = tid;
        float s   = ppS [tl*C_ + c];
        float s2  = ppS2[tl*C_ + c];
        float m   = s / (float)NRED;
        float var = s2 / (float)NRED - m*m;
        float rs  = rsqrtf(var + EPS);
        float g   = gamma[tl*C_ + c];
        scale[c]  = g * rs;
        shiftv[c] = beta[tl*C_ + c] - m * rs * g;
    }
    {
        const float* wsrc = conv_w + (long)tl * (C_*C_*9);
        for (int f = tid; f < C_*C_*9; f += 512) {
            int co  = f / 288;
            int rem = f - co*288;
            int cin = rem / 9;
            int tap = rem - cin*9;
            wlds[(tap*WSL + co)*HP + cin] = (__bf16)wsrc[f];
        }
    }
    __syncthreads();

    for (int idx = tid; idx < 4*NPIX; idx += 512) {
        int cg = idx / NPIX;
        int p  = idx - cg*NPIX;
        int y  = p / 20;
        int xx = p - y*20;
        int c0 = cg*8;
        const float* ps = x + (((long)(b*C_ + c0)*H_ + ti + y)*W_ + tj + xx);
        float v[8];
        #pragma unroll
        for (int k = 0; k < 8; ++k) v[k] = ps[k * (H_*W_)];
        bf16x8 h;
        #pragma unroll
        for (int k = 0; k < 8; ++k)
            h[k] = (__bf16)fmaxf(v[k]*scale[c0+k] + shiftv[c0+k], 0.f);
        *(bf16x8*)&hlds[((y+1)*22 + xx + 1)*HP + c0] = h;
    }
    __syncthreads();

    int lane = tid & 63;
    int wv   = tid >> 6;
    int mm   = lane & 15;
    int jg   = lane >> 4;
    int j0   = jg * 8;
    float b0 = conv_b[tl*C_ + mm];
    float b1 = conv_b[tl*C_ + 16 + mm];

    auto store_chunk = [&](int chunk, f32x4 a0, f32x4 a1) {
        int pb = chunk*16 + jg*4;
        int py = pb / 20;
        int px = pb - py*20;
        long o0 = ((long)(b*C_ + mm)*H_ + ti + py)*W_ + tj + px;
        long o1 = o0 + (long)16*H_*W_;
        float4 x0 = *(const float4*)&x[o0];
        float4 x1 = *(const float4*)&x[o1];
        float4 r0 = make_float4(a0[0]+x0.x, a0[1]+x0.y, a0[2]+x0.z, a0[3]+x0.w);
        float4 r1 = make_float4(a1[0]+x1.x, a1[1]+x1.y, a1[2]+x1.z, a1[3]+x1.w);
        *(float4*)&out[o0] = r0;
        *(float4*)&out[o1] = r1;
    };

    const __bf16* ab[3];
    #pragma unroll
    for (int i = 0; i < 3; ++i) {
        int p  = (wv + 8*i)*16 + mm;
        int py = p / 20;
        int px = p - py*20;
        ab[i] = &hlds[(py*22 + px)*HP + j0];
    }
    f32x4 acc[3][2];
    #pragma unroll
    for (int i = 0; i < 3; ++i) {
        acc[i][0] = f32x4{b0,b0,b0,b0};
        acc[i][1] = f32x4{b1,b1,b1,b1};
    }
    #pragma unroll
    for (int tap = 0; tap < 9; ++tap) {
        const int ky = tap/3, kx = tap - (tap/3)*3;
        bf16x8 w0 = *(const bf16x8*)&wlds[(tap*WSL + mm)*HP + j0];
        bf16x8 w1 = *(const bf16x8*)&wlds[(tap*WSL + 16 + mm)*HP + j0];
        #pragma unroll
        for (int i = 0; i < 3; ++i) {
            bf16x8 af = *(const bf16x8*)(ab[i] + (ky*22 + kx)*HP);
            acc[i][0] = __builtin_amdgcn_mfma_f32_16x16x32_bf16(af, w0, acc[i][0], 0, 0, 0);
            acc[i][1] = __builtin_amdgcn_mfma_f32_16x16x32_bf16(af, w1, acc[i][1], 0, 0, 0);
        }
    }
    #pragma unroll
    for (int i = 0; i < 3; ++i) store_chunk(wv + 8*i, acc[i][0], acc[i][1]);

    if (wv == 0) {
        int p  = 24*16 + mm;
        int py = p / 20;
        int px = p - py*20;
        const __bf16* a3 = &hlds[(py*22 + px)*HP + j0];
        f32x4 c0v = f32x4{b0,b0,b0,b0};
        f32x4 c1v = f32x4{b1,b1,b1,b1};
        #pragma unroll
        for (int tap = 0; tap < 9; ++tap) {
            const int ky = tap/3, kx = tap - (tap/3)*3;
            bf16x8 w0 = *(const bf16x8*)&wlds[(tap*WSL + mm)*HP + j0];
            bf16x8 w1 = *(const bf16x8*)&wlds[(tap*WSL + 16 + mm)*HP + j0];
            bf16x8 af = *(const bf16x8*)(a3 + (ky*22 + kx)*HP);
            c0v = __builtin_amdgcn_mfma_f32_16x16x32_bf16(af, w0, c0v, 0, 0, 0);
            c1v = __builtin_amdgcn_mfma_f32_16x16x32_bf16(af, w1, c1v, 0, 0, 0);
        }
        store_chunk(24, c0v, c1v);
    }
}

extern "C" void kernel_launch(void* const* d_in, const int* in_sizes, int n_in,
                              void* d_out, int out_size, void* d_ws, size_t ws_size,
                              hipStream_t stream) {
    const float* x      = (const float*)d_in[0];
    const float* gamma  = (const float*)d_in[1];
    const float* beta   = (const float*)d_in[2];
    const float* conv_w = (const float*)d_in[3];
    const float* conv_b = (const float*)d_in[4];
    float* out = (float*)d_out;

    float*  ppS   = (float*)d_ws;                    // 2048 floats
    float*  ppS2  = ppS + NT*C_;                     // 2048 floats
    size_t  statsBytes = (size_t)2 * NT * C_ * sizeof(float);
    __bf16* wpack = (__bf16*)((char*)d_ws + statsBytes);
    size_t  need  = statsBytes + (size_t)NT * WPACK_PER_TILE * sizeof(__bf16);

    hipMemsetAsync(d_ws, 0, statsBytes, stream);
    if (ws_size >= need) {
        statsA_kernel<<<B_*C_ + NT, 320, 0, stream>>>(x, ppS, ppS2, conv_w, wpack);
        fused_packed<<<NT * B_, 512, 0, stream>>>(x, gamma, beta, conv_b,
                                                  ppS, ppS2, wpack, out);
    } else {
        statsA_kernel<<<B_*C_, 320, 0, stream>>>(x, ppS, ppS2, conv_w, wpack);
        fused_lds<<<NT * B_, 512, 0, stream>>>(x, gamma, beta, conv_w, conv_b,
                                               ppS, ppS2, out);
    }
}

// Round 4
// 278.080 us; speedup vs baseline: 1.0616x; 1.0616x over previous
//
#include <hip/hip_runtime.h>

#define NT 64
#define B_ 32
#define C_ 32
#define H_ 160
#define W_ 160
#define TH 20
#define TW 20
#define NPIX (TH*TW)     // 400
#define NRED (B_*NPIX)   // 12800
#define EPS 1e-5f

#define HP 40            // hlds channel stride (bf16)
#define WSL 33           // (fallback kernel only) wlds per-tap slab stride in co rows
#define WPACK_PER_TILE (9*2*64*8)   // 9216 bf16 per tile

typedef __bf16 bf16x8 __attribute__((ext_vector_type(8)));
typedef float  f32x4  __attribute__((ext_vector_type(4)));

// ============ Kernel A: half-plane stats (2 blocks/plane) + weight pre-pack
// Blocks [0, 2048): stats for half-plane (b,c,half). Blocks [2048, 2112):
// pack tile tl's weights into per-lane B-fragment order [tap][half][lane][8].
__global__ __launch_bounds__(320) void statsA_kernel(const float* __restrict__ x,
                                                     float* __restrict__ ppS,
                                                     float* __restrict__ ppS2,
                                                     const float* __restrict__ conv_w,
                                                     __bf16* __restrict__ wpack) {
    int blk = blockIdx.x;
    if (blk >= 2*B_*C_) {
        int tl = blk - 2*B_*C_;
        const float* wsrc = conv_w + (long)tl * (C_*C_*9);
        __bf16* wdst = wpack + (long)tl * WPACK_PER_TILE;
        for (int f = threadIdx.x; f < WPACK_PER_TILE; f += 320) {
            int t    = f >> 10;          // tap 0..8
            int r    = f & 1023;
            int h    = r >> 9;           // co half 0..1
            int r2   = r & 511;
            int lane = r2 >> 3;          // 0..63
            int k    = r2 & 7;
            int mm   = lane & 15;
            int jg   = lane >> 4;
            int co   = h*16 + mm;
            int cin  = jg*8 + k;
            wdst[f] = (__bf16)wsrc[(co*C_ + cin)*9 + t];
        }
        return;
    }
    int half = blk & 1;            // top/bottom 80 rows
    int pc   = blk >> 1;           // plane 0..1023
    int b = pc >> 5;
    int c = pc & 31;
    const float* plane = x + ((long)(b*C_ + c)) * H_ * W_ + (long)half * 80 * W_;

    int tid   = threadIdx.x;
    int col4  = tid % 40;          // f4 column (0..39)
    int rbase = tid / 40;          // 0..7

    __shared__ float sh [4 * 321];
    __shared__ float sh2[4 * 321];

    for (int tr = 0; tr < 4; ++tr) {       // 4 tile-rows per half-plane
        float s = 0.f, s2 = 0.f;
        #pragma unroll
        for (int k = 0; k < 3; ++k) {
            int r20 = rbase + 8*k;
            if (r20 < 20) {
                int row = tr*20 + r20;
                float4 v = *(const float4*)(plane + row*W_ + col4*4);
                s  += v.x + v.y + v.z + v.w;
                s2 += v.x*v.x + v.y*v.y + v.z*v.z + v.w*v.w;
            }
        }
        sh [tr*321 + tid] = s;
        sh2[tr*321 + tid] = s2;
    }
    __syncthreads();

    if (tid < 32) {
        int tr = tid >> 3, tc = tid & 7;
        float ps = 0.f, ps2 = 0.f;
        #pragma unroll
        for (int rb = 0; rb < 8; ++rb)
            #pragma unroll
            for (int c5 = 0; c5 < 5; ++c5) {
                int t = tr*321 + rb*40 + tc*5 + c5;
                ps += sh[t]; ps2 += sh2[t];
            }
        int tl = (half*4 + tr)*8 + tc;
        atomicAdd(&ppS [tl*C_ + c], ps);
        atomicAdd(&ppS2[tl*C_ + c], ps2);
    }
}

// ============ Kernel B (packed path): norm+relu + 9-tap MFMA conv + residual
// v4: same as v3 but __launch_bounds__(512,6) -> 3 blocks/CU, reg cap ~80
// incl. AGPRs (v3's (512,8) forced a 64-reg cap -> scratch spills -> +110 MB
// HBM traffic). LDS = hlds only (38,976 B).
__global__ __launch_bounds__(512, 6) void fused_packed(
        const float* __restrict__ x,
        const float* __restrict__ gamma,
        const float* __restrict__ beta,
        const float* __restrict__ conv_b,
        const float* __restrict__ ppS,
        const float* __restrict__ ppS2,
        const __bf16* __restrict__ wpack,
        float* __restrict__ out) {
    int blk = blockIdx.x;
    int tl = blk >> 5;
    int b  = blk & 31;
    int ti = (tl >> 3) * TH;
    int tj = (tl & 7)  * TW;
    int tid = threadIdx.x;

    // LDS: hlds [484 pix][40 ch] bf16 (zero halo ring) + BN coeffs
    __shared__ __align__(16) unsigned char smem[38976];
    __bf16* hlds   = (__bf16*)smem;
    float*  scale  = (float*)(smem + 38720);
    float*  shiftv = (float*)(smem + 38848);

    // ---- phase 0: zero halo ring + finalize BN coeffs ----
    if (tid < 420) {                       // 84 halo pixels x 5 uint4 (80 B each)
        int hp = tid / 5, q = tid - hp*5;
        int P;
        if      (hp < 22) P = hp;                    // row 0
        else if (hp < 44) P = 462 + (hp - 22);       // row 21
        else if (hp < 64) P = (hp - 43) * 22;        // col 0, rows 1..20
        else              P = (hp - 63) * 22 + 21;   // col 21, rows 1..20
        ((uint4*)smem)[P*5 + q] = uint4{0,0,0,0};
    }
    if (tid < C_) {
        int c = tid;
        float s   = ppS [tl*C_ + c];
        float s2  = ppS2[tl*C_ + c];
        float m   = s / (float)NRED;
        float var = s2 / (float)NRED - m*m;
        float rs  = rsqrtf(var + EPS);
        float g   = gamma[tl*C_ + c];
        scale[c]  = g * rs;
        shiftv[c] = beta[tl*C_ + c] - m * rs * g;
    }
    __syncthreads();

    // ---- phase 1: normalize+relu, 1 pixel x 8 channels per item, b128 write
    for (int idx = tid; idx < 4*NPIX; idx += 512) {   // 1600 items
        int cg = idx / NPIX;            // channel group 0..3
        int p  = idx - cg*NPIX;         // pixel 0..399 (lane-consecutive)
        int y  = p / 20;
        int xx = p - y*20;
        int c0 = cg*8;
        const float* ps = x + (((long)(b*C_ + c0)*H_ + ti + y)*W_ + tj + xx);
        float v[8];
        #pragma unroll
        for (int k = 0; k < 8; ++k) v[k] = ps[k * (H_*W_)];
        bf16x8 h;
        #pragma unroll
        for (int k = 0; k < 8; ++k)
            h[k] = (__bf16)fmaxf(v[k]*scale[c0+k] + shiftv[c0+k], 0.f);
        *(bf16x8*)&hlds[((y+1)*22 + xx + 1)*HP + c0] = h;
    }
    __syncthreads();

    // ---- phase 2: tap-outer GEMM; W from packed global (L2-hot), A from hlds
    int lane = tid & 63;
    int wv   = tid >> 6;            // wave 0..7
    int mm   = lane & 15;
    int jg   = lane >> 4;           // 0..3
    int j0   = jg * 8;
    float b0 = conv_b[tl*C_ + mm];
    float b1 = conv_b[tl*C_ + 16 + mm];
    const __bf16* wp = wpack + (long)tl * WPACK_PER_TILE + lane*8;

    auto store_chunk = [&](int chunk, f32x4 a0, f32x4 a1) {
        // D layout: col = lane&15 (co), row = jg*4 + r (pixel) -> 4 consecutive
        // pixels; runs of 4 never cross the 20-wide tile row.
        int pb = chunk*16 + jg*4;
        int py = pb / 20;
        int px = pb - py*20;
        long o0 = ((long)(b*C_ + mm)*H_ + ti + py)*W_ + tj + px;
        long o1 = o0 + (long)16*H_*W_;
        float4 x0 = *(const float4*)&x[o0];     // residual: L2/L3-hot
        float4 x1 = *(const float4*)&x[o1];
        float4 r0 = make_float4(a0[0]+x0.x, a0[1]+x0.y, a0[2]+x0.z, a0[3]+x0.w);
        float4 r1 = make_float4(a1[0]+x1.x, a1[1]+x1.y, a1[2]+x1.z, a1[3]+x1.w);
        *(float4*)&out[o0] = r0;
        *(float4*)&out[o1] = r1;
    };

    // 3 chunks per wave (chunk = wv + 8*i); wave 0 takes chunk 24 afterwards
    const __bf16* ab[3];
    #pragma unroll
    for (int i = 0; i < 3; ++i) {
        int p  = (wv + 8*i)*16 + mm;
        int py = p / 20;
        int px = p - py*20;
        ab[i] = &hlds[(py*22 + px)*HP + j0];
    }
    f32x4 acc[3][2];
    #pragma unroll
    for (int i = 0; i < 3; ++i) {
        acc[i][0] = f32x4{b0,b0,b0,b0};
        acc[i][1] = f32x4{b1,b1,b1,b1};
    }
    #pragma unroll
    for (int tap = 0; tap < 9; ++tap) {
        const int ky = tap/3, kx = tap - (tap/3)*3;
        bf16x8 w0 = *(const bf16x8*)(wp + tap*1024);
        bf16x8 w1 = *(const bf16x8*)(wp + tap*1024 + 512);
        #pragma unroll
        for (int i = 0; i < 3; ++i) {
            bf16x8 af = *(const bf16x8*)(ab[i] + (ky*22 + kx)*HP);
            acc[i][0] = __builtin_amdgcn_mfma_f32_16x16x32_bf16(af, w0, acc[i][0], 0, 0, 0);
            acc[i][1] = __builtin_amdgcn_mfma_f32_16x16x32_bf16(af, w1, acc[i][1], 0, 0, 0);
        }
    }
    #pragma unroll
    for (int i = 0; i < 3; ++i) store_chunk(wv + 8*i, acc[i][0], acc[i][1]);

    if (wv == 0) {   // wave-uniform branch: the 25th chunk
        int p  = 24*16 + mm;
        int py = p / 20;
        int px = p - py*20;
        const __bf16* a3 = &hlds[(py*22 + px)*HP + j0];
        f32x4 c0v = f32x4{b0,b0,b0,b0};
        f32x4 c1v = f32x4{b1,b1,b1,b1};
        #pragma unroll
        for (int tap = 0; tap < 9; ++tap) {
            const int ky = tap/3, kx = tap - (tap/3)*3;
            bf16x8 w0 = *(const bf16x8*)(wp + tap*1024);
            bf16x8 w1 = *(const bf16x8*)(wp + tap*1024 + 512);
            bf16x8 af = *(const bf16x8*)(a3 + (ky*22 + kx)*HP);
            c0v = __builtin_amdgcn_mfma_f32_16x16x32_bf16(af, w0, c0v, 0, 0, 0);
            c1v = __builtin_amdgcn_mfma_f32_16x16x32_bf16(af, w1, c1v, 0, 0, 0);
        }
        store_chunk(24, c0v, c1v);
    }
}

// ============ Kernel B (fallback, ws too small): R1 v2 kernel verbatim =====
__global__ __launch_bounds__(512, 4) void fused_lds(
        const float* __restrict__ x,
        const float* __restrict__ gamma,
        const float* __restrict__ beta,
        const float* __restrict__ conv_w,
        const float* __restrict__ conv_b,
        const float* __restrict__ ppS,
        const float* __restrict__ ppS2,
        float* __restrict__ out) {
    int blk = blockIdx.x;
    int tl = blk >> 5;
    int b  = blk & 31;
    int ti = (tl >> 3) * TH;
    int tj = (tl & 7)  * TW;
    int tid = threadIdx.x;

    __shared__ __align__(16) unsigned char smem[62656];
    __bf16* hlds   = (__bf16*)smem;
    __bf16* wlds   = (__bf16*)(smem + 38720);
    float*  scale  = (float*)(smem + 62400);
    float*  shiftv = (float*)(smem + 62528);

    if (tid < 420) {
        int hp = tid / 5, q = tid - hp*5;
        int P;
        if      (hp < 22) P = hp;
        else if (hp < 44) P = 462 + (hp - 22);
        else if (hp < 64) P = (hp - 43) * 22;
        else              P = (hp - 63) * 22 + 21;
        ((uint4*)smem)[P*5 + q] = uint4{0,0,0,0};
    }
    if (tid < C_) {
        int c = tid;
        float s   = ppS [tl*C_ + c];
        float s2  = ppS2[tl*C_ + c];
        float m   = s / (float)NRED;
        float var = s2 / (float)NRED - m*m;
        float rs  = rsqrtf(var + EPS);
        float g   = gamma[tl*C_ + c];
        scale[c]  = g * rs;
        shiftv[c] = beta[tl*C_ + c] - m * rs * g;
    }
    {
        const float* wsrc = conv_w + (long)tl * (C_*C_*9);
        for (int f = tid; f < C_*C_*9; f += 512) {
            int co  = f / 288;
            int rem = f - co*288;
            int cin = rem / 9;
            int tap = rem - cin*9;
            wlds[(tap*WSL + co)*HP + cin] = (__bf16)wsrc[f];
        }
    }
    __syncthreads();

    for (int idx = tid; idx < 4*NPIX; idx += 512) {
        int cg = idx / NPIX;
        int p  = idx - cg*NPIX;
        int y  = p / 20;
        int xx = p - y*20;
        int c0 = cg*8;
        const float* ps = x + (((long)(b*C_ + c0)*H_ + ti + y)*W_ + tj + xx);
        float v[8];
        #pragma unroll
        for (int k = 0; k < 8; ++k) v[k] = ps[k * (H_*W_)];
        bf16x8 h;
        #pragma unroll
        for (int k = 0; k < 8; ++k)
            h[k] = (__bf16)fmaxf(v[k]*scale[c0+k] + shiftv[c0+k], 0.f);
        *(bf16x8*)&hlds[((y+1)*22 + xx + 1)*HP + c0] = h;
    }
    __syncthreads();

    int lane = tid & 63;
    int wv   = tid >> 6;
    int mm   = lane & 15;
    int jg   = lane >> 4;
    int j0   = jg * 8;
    float b0 = conv_b[tl*C_ + mm];
    float b1 = conv_b[tl*C_ + 16 + mm];

    auto store_chunk = [&](int chunk, f32x4 a0, f32x4 a1) {
        int pb = chunk*16 + jg*4;
        int py = pb / 20;
        int px = pb - py*20;
        long o0 = ((long)(b*C_ + mm)*H_ + ti + py)*W_ + tj + px;
        long o1 = o0 + (long)16*H_*W_;
        float4 x0 = *(const float4*)&x[o0];
        float4 x1 = *(const float4*)&x[o1];
        float4 r0 = make_float4(a0[0]+x0.x, a0[1]+x0.y, a0[2]+x0.z, a0[3]+x0.w);
        float4 r1 = make_float4(a1[0]+x1.x, a1[1]+x1.y, a1[2]+x1.z, a1[3]+x1.w);
        *(float4*)&out[o0] = r0;
        *(float4*)&out[o1] = r1;
    };

    const __bf16* ab[3];
    #pragma unroll
    for (int i = 0; i < 3; ++i) {
        int p  = (wv + 8*i)*16 + mm;
        int py = p / 20;
        int px = p - py*20;
        ab[i] = &hlds[(py*22 + px)*HP + j0];
    }
    f32x4 acc[3][2];
    #pragma unroll
    for (int i = 0; i < 3; ++i) {
        acc[i][0] = f32x4{b0,b0,b0,b0};
        acc[i][1] = f32x4{b1,b1,b1,b1};
    }
    #pragma unroll
    for (int tap = 0; tap < 9; ++tap) {
        const int ky = tap/3, kx = tap - (tap/3)*3;
        bf16x8 w0 = *(const bf16x8*)&wlds[(tap*WSL + mm)*HP + j0];
        bf16x8 w1 = *(const bf16x8*)&wlds[(tap*WSL + 16 + mm)*HP + j0];
        #pragma unroll
        for (int i = 0; i < 3; ++i) {
            bf16x8 af = *(const bf16x8*)(ab[i] + (ky*22 + kx)*HP);
            acc[i][0] = __builtin_amdgcn_mfma_f32_16x16x32_bf16(af, w0, acc[i][0], 0, 0, 0);
            acc[i][1] = __builtin_amdgcn_mfma_f32_16x16x32_bf16(af, w1, acc[i][1], 0, 0, 0);
        }
    }
    #pragma unroll
    for (int i = 0; i < 3; ++i) store_chunk(wv + 8*i, acc[i][0], acc[i][1]);

    if (wv == 0) {
        int p  = 24*16 + mm;
        int py = p / 20;
        int px = p - py*20;
        const __bf16* a3 = &hlds[(py*22 + px)*HP + j0];
        f32x4 c0v = f32x4{b0,b0,b0,b0};
        f32x4 c1v = f32x4{b1,b1,b1,b1};
        #pragma unroll
        for (int tap = 0; tap < 9; ++tap) {
            const int ky = tap/3, kx = tap - (tap/3)*3;
            bf16x8 w0 = *(const bf16x8*)&wlds[(tap*WSL + mm)*HP + j0];
            bf16x8 w1 = *(const bf16x8*)&wlds[(tap*WSL + 16 + mm)*HP + j0];
            bf16x8 af = *(const bf16x8*)(a3 + (ky*22 + kx)*HP);
            c0v = __builtin_amdgcn_mfma_f32_16x16x32_bf16(af, w0, c0v, 0, 0, 0);
            c1v = __builtin_amdgcn_mfma_f32_16x16x32_bf16(af, w1, c1v, 0, 0, 0);
        }
        store_chunk(24, c0v, c1v);
    }
}

extern "C" void kernel_launch(void* const* d_in, const int* in_sizes, int n_in,
                              void* d_out, int out_size, void* d_ws, size_t ws_size,
                              hipStream_t stream) {
    const float* x      = (const float*)d_in[0];
    const float* gamma  = (const float*)d_in[1];
    const float* beta   = (const float*)d_in[2];
    const float* conv_w = (const float*)d_in[3];
    const float* conv_b = (const float*)d_in[4];
    float* out = (float*)d_out;

    float*  ppS   = (float*)d_ws;                    // 2048 floats
    float*  ppS2  = ppS + NT*C_;                     // 2048 floats
    size_t  statsBytes = (size_t)2 * NT * C_ * sizeof(float);
    __bf16* wpack = (__bf16*)((char*)d_ws + statsBytes);
    size_t  need  = statsBytes + (size_t)NT * WPACK_PER_TILE * sizeof(__bf16);

    hipMemsetAsync(d_ws, 0, statsBytes, stream);
    if (ws_size >= need) {
        statsA_kernel<<<2*B_*C_ + NT, 320, 0, stream>>>(x, ppS, ppS2, conv_w, wpack);
        fused_packed<<<NT * B_, 512, 0, stream>>>(x, gamma, beta, conv_b,
                                                  ppS, ppS2, wpack, out);
    } else {
        statsA_kernel<<<2*B_*C_, 320, 0, stream>>>(x, ppS, ppS2, conv_w, wpack);
        fused_lds<<<NT * B_, 512, 0, stream>>>(x, gamma, beta, conv_w, conv_b,
                                               ppS, ppS2, out);
    }
}